// Round 13
// baseline (5280.133 us; speedup 1.0000x reference)
//
#include <hip/hip_runtime.h>
#include <stdint.h>

#define DEVI __device__ __forceinline__

typedef unsigned short u16;
typedef __bf16 bf16x8 __attribute__((ext_vector_type(8)));
typedef float f32x4 __attribute__((ext_vector_type(4)));
typedef u16 u16x8 __attribute__((ext_vector_type(8)));

DEVI u16 f2bf(float f){
  union { float f; unsigned u; } v; v.f = f;
  unsigned r = v.u + 0x7FFFu + ((v.u >> 16) & 1u);
  return (u16)(r >> 16);
}
DEVI float bf2f(u16 h){
  union { unsigned u; float f; } v; v.u = ((unsigned)h) << 16;
  return v.f;
}
DEVI float lky(float t){ return t > 0.f ? t : 0.2f * t; }

#define GLD16(gp, lp) __builtin_amdgcn_global_load_lds( \
    (const __attribute__((address_space(1))) void*)(gp), \
    (__attribute__((address_space(3))) void*)(lp), 16, 0, 0)

// ===========================================================================
// gemmV: gemmU (R12-proven: 256x256, BK=64, 16 waves 4x4, wave tile 64x64,
// acc 64 VGPR -> 4 waves/SIMD, conflict-free slot^(row&7) swizzle, 128KB
// dbuf, one barrier-pair per K-tile) with A read DIRECTLY as f32:
//   per thread/tile: 4x f32x4 loads (pre-swizzled col, issued at body top,
//   ~2500cy MFMA cover) -> f2bf (bit-identical to the old cvt kernels) ->
//   2x linear ds_write_b128 after MFMA -> vmcnt(0)+lgkmcnt(0) before barrier.
// Kills k_cvt_sww + cgw/dww cvt kernels (~240us) and the 167MB Wb buffer.
// Register math: acc 64 + frags 32 + ra 16 + addr ~16 ~= 128 cap @ (1024,4).
// Failure signature (pre-registered): VGPR=128 + WRITE_SIZE blowup = spill.
// STACKED: A row r<8976 -> sww[r][0..4424); else sww[r-8976][4424..8848).
// EPI 0: C[n*ldc+o]=acc | EPI 2: leaky(acc*scale+off) + fused co1 reduction
// EPI 3: diagonal-only llw reduction (mask_mat = eye).
// ===========================================================================
template<int EPI, int STACKED>
__global__ __launch_bounds__(1024, 4)
void gemmV(const float* __restrict__ A, int Astride, int Kreal, int Mrows,
           const u16* __restrict__ B,
           int Kp, int Nt, int SN, int Mreal, float* __restrict__ C, long long ldc,
           const float* __restrict__ bias, const float* __restrict__ scale,
           const float* __restrict__ off, const float* __restrict__ llw,
           float* __restrict__ oacc)
{
  __shared__ __align__(16) u16 As[2][16384];   // 256 rows x 64 cols bf16
  __shared__ __align__(16) u16 Bs[2][16384];
  const int t    = threadIdx.x;                // 0..1023
  const int lane = t & 63;
  const int wid  = t >> 6;                     // 0..15
  const int wr = wid >> 2, wc = wid & 3;       // 4 x 4 waves
  const int l4 = lane >> 4, l15 = lane & 15;

  // bijective XCD swizzle (m204 variant)
  const int nwg = gridDim.x;
  const int xc = blockIdx.x & 7, pp = blockIdx.x >> 3;
  const int qq = nwg >> 3, rr = nwg & 7;
  const int wg = (xc < rr ? xc*(qq+1) : rr*(qq+1) + (xc-rr)*qq) + pp;
  // supertile: strips of SN nt-columns, mt-major inside a strip
  const int strip_sz = (nwg / Nt) * SN;
  const int strip = wg / strip_sz, srem = wg % strip_sz;
  const int mt = srem / SN, nt = strip*SN + srem % SN;

  const int am0 = mt*256;
  const size_t bn0 = (size_t)nt*256;

  f32x4 acc[4][4];
  #pragma unroll
  for (int i = 0; i < 4; ++i)
    #pragma unroll
    for (int j = 0; j < 4; ++j) acc[i][j] = f32x4{0.f,0.f,0.f,0.f};
  bf16x8 afr[4], bfr[4];

  const int NT = Kp >> 6;                      // 64-wide K tiles (even)

  // staging geometry: sweep j covers rows j*128 + (t>>3), slot t&7;
  // linear LDS dest (j*8192 + t*8 u16), pre-swizzled source column.
  const int trl = t >> 3, tsl = t & 7;
  const int scol = ((tsl ^ (trl & 7)) * 8);    // (trl+128)&7 == trl&7
  const u16* pB0 = B + (bn0 + trl)*(size_t)Kp + scol;
  const u16* pB1 = B + (bn0 + trl + 128)*(size_t)Kp + scol;

  // A (f32) per-sweep bases with STACKED remap + row guards
  const int row0 = am0 + trl;
  const int row1 = row0 + 128;
  int ro0 = row0, ko0 = 0, ro1 = row1, ko1 = 0;
  if (STACKED){
    if (row0 >= 8976){ ro0 = row0 - 8976; ko0 = 4424; }
    if (row1 >= 8976){ ro1 = row1 - 8976; ko1 = 4424; }
  }
  const bool okr0 = row0 < Mrows, okr1 = row1 < Mrows;
  const float* pA0 = A + (size_t)(okr0 ? ro0 : 0)*Astride + (okr0 ? ko0 : 0) + scol;
  const float* pA1 = A + (size_t)(okr1 ? ro1 : 0)*Astride + (okr1 ? ko1 : 0) + scol;

  f32x4 ra0a, ra0b, ra1a, ra1b;
  auto ALOAD = [&](int kc){
    const bool okc = (kc + scol) < Kreal;      // chunks are 8-f32 aligned
    const f32x4 z = {0.f,0.f,0.f,0.f};
    const bool ok0 = okr0 && okc, ok1 = okr1 && okc;
    ra0a = ok0 ? *(const f32x4*)(pA0 + kc)     : z;
    ra0b = ok0 ? *(const f32x4*)(pA0 + kc + 4) : z;
    ra1a = ok1 ? *(const f32x4*)(pA1 + kc)     : z;
    ra1b = ok1 ? *(const f32x4*)(pA1 + kc + 4) : z;
  };
  auto AWRITE = [&](int buf){
    u16x8 w0 = { f2bf(ra0a[0]),f2bf(ra0a[1]),f2bf(ra0a[2]),f2bf(ra0a[3]),
                 f2bf(ra0b[0]),f2bf(ra0b[1]),f2bf(ra0b[2]),f2bf(ra0b[3]) };
    u16x8 w1 = { f2bf(ra1a[0]),f2bf(ra1a[1]),f2bf(ra1a[2]),f2bf(ra1a[3]),
                 f2bf(ra1b[0]),f2bf(ra1b[1]),f2bf(ra1b[2]),f2bf(ra1b[3]) };
    *(u16x8*)&As[buf][t*8] = w0;
    *(u16x8*)&As[buf][8192 + t*8] = w1;
  };
  auto BSTAGE = [&](int kc, int buf){
    u16* lb = &Bs[buf][0];
    GLD16(pB0 + kc, lb + t*8);
    GLD16(pB1 + kc, lb + 8192 + t*8);
  };

  // frag read offsets (u16 units); XOR distributes over *8 (slot < 8):
  // offset = base ^ ((ks*4+l4)*8)
  int aoff[4], boff[4];
  #pragma unroll
  for (int mi = 0; mi < 4; ++mi){
    const int r = wr*64 + mi*16 + l15;
    aoff[mi] = r*64 + ((r & 7)*8);
  }
  #pragma unroll
  for (int ni = 0; ni < 4; ++ni){
    const int r = wc*64 + ni*16 + l15;
    boff[ni] = r*64 + ((r & 7)*8);
  }

  // prologue: tile0 -> buf0
  ALOAD(0);
  BSTAGE(0, 0);
  AWRITE(0);                                   // waits A loads (compiler)
  asm volatile("s_waitcnt vmcnt(0) lgkmcnt(0)" ::: "memory");
  __builtin_amdgcn_s_barrier();

  #define GV_BODY(KT, RB_, WB_)                                              \
  {                                                                          \
    const int nx = ((KT)+1 < NT) ? (KT)+1 : NT-1;                            \
    ALOAD(nx*64);                                                            \
    BSTAGE(nx*64, WB_);                                                      \
    const u16* ab = &As[RB_][0];                                             \
    const u16* bb = &Bs[RB_][0];                                             \
    _Pragma("unroll")                                                        \
    for (int ks = 0; ks < 2; ++ks){                                          \
      const int sx = (ks*4 + l4)*8;                                          \
      _Pragma("unroll")                                                      \
      for (int mi = 0; mi < 4; ++mi)                                         \
        afr[mi] = *(const bf16x8*)&ab[aoff[mi] ^ sx];                        \
      _Pragma("unroll")                                                      \
      for (int ni = 0; ni < 4; ++ni)                                         \
        bfr[ni] = *(const bf16x8*)&bb[boff[ni] ^ sx];                        \
      __builtin_amdgcn_s_setprio(1);                                         \
      _Pragma("unroll")                                                      \
      for (int mi = 0; mi < 4; ++mi)                                         \
        _Pragma("unroll")                                                    \
        for (int ni = 0; ni < 4; ++ni)                                       \
          acc[mi][ni] = __builtin_amdgcn_mfma_f32_16x16x32_bf16(             \
              afr[mi], bfr[ni], acc[mi][ni], 0, 0, 0);                       \
      __builtin_amdgcn_s_setprio(0);                                         \
    }                                                                        \
    AWRITE(WB_);                                                             \
    asm volatile("s_waitcnt vmcnt(0) lgkmcnt(0)" ::: "memory");              \
    __builtin_amdgcn_s_barrier();                                            \
  }

  for (int kt = 0; kt < NT; kt += 2){
    GV_BODY(kt,   0, 1);
    GV_BODY(kt+1, 1, 0);
  }
  #undef GV_BODY

  const int ob0 = mt*256 + wr*64;
  const int nb0 = nt*256 + wc*64;

  if (EPI == 0){
    #pragma unroll
    for (int mi = 0; mi < 4; ++mi){
      const int ob = ob0 + mi*16 + l4*4;
      if (ob < Mreal){
        #pragma unroll
        for (int ni = 0; ni < 4; ++ni){
          const int n = nb0 + ni*16 + l15;
          *(f32x4*)&C[(size_t)n*ldc + ob] = acc[mi][ni];
        }
      }
    }
  } else if (EPI == 2){
    // glb2 store + fused co1[n][a] += sum_c cow[a][c]*glb2[n][c] partials
    #pragma unroll
    for (int ni = 0; ni < 4; ++ni){
      const int n = nb0 + ni*16 + l15;
      float sa0=0.f, sa1=0.f, sa2=0.f, sa3=0.f;
      #pragma unroll
      for (int mi = 0; mi < 4; ++mi){
        const int ob = ob0 + mi*16 + l4*4;
        if (ob < Mreal){
          const float sc0=scale[ob],sc1=scale[ob+1],sc2=scale[ob+2],sc3=scale[ob+3];
          const float of0=off[ob],of1=off[ob+1],of2=off[ob+2],of3=off[ob+3];
          f32x4 a = acc[mi][ni];
          f32x4 vv = { lky(a[0]*sc0+of0), lky(a[1]*sc1+of1),
                       lky(a[2]*sc2+of2), lky(a[3]*sc3+of3) };
          *(f32x4*)&C[(size_t)n*ldc + ob] = vv;
          #pragma unroll
          for (int r = 0; r < 4; ++r){
            const float vr = vv[r];
            sa0 += llw[(size_t)0*17952 + ob + r] * vr;   // llw == cow here
            sa1 += llw[(size_t)1*17952 + ob + r] * vr;
            sa2 += llw[(size_t)2*17952 + ob + r] * vr;
            sa3 += llw[(size_t)3*17952 + ob + r] * vr;
          }
        }
      }
      float sv[4] = {sa0,sa1,sa2,sa3};
      #pragma unroll
      for (int a4 = 0; a4 < 4; ++a4){
        float tt = sv[a4];
        tt += __shfl_xor(tt, 16);
        tt += __shfl_xor(tt, 32);
        if (l4 == 0) atomicAdd(&oacc[n*4 + a4], tt);     // oacc == co1acc
      }
    }
  } else { // EPI == 3: diagonal-only (mask_mat = eye)
    #pragma unroll
    for (int ni = 0; ni < 4; ++ni){
      const int n = nb0 + ni*16 + l15;
      const int m = n & 3, q = n >> 2;
      float s = 0.f;
      #pragma unroll
      for (int mi = 0; mi < 4; ++mi){
        #pragma unroll
        for (int r = 0; r < 4; ++r){
          const int o = ob0 + mi*16 + l4*4 + r;
          if (o < Mreal){
            const float val = lky(acc[mi][ni][r] + bias[o]);
            s += llw[(size_t)m*8976 + o] * val;
          }
        }
      }
      s += __shfl_xor(s, 16);
      s += __shfl_xor(s, 32);
      if (l4 == 0) atomicAdd(&oacc[(q*4 + m)*4 + m], s);
    }
  }
}

// --- small 128x128 GEMM for v_pre (C[o][n]+bias) -----------------------------
__global__ __launch_bounds__(256)
void gemm_vpre(const u16* __restrict__ A, const u16* __restrict__ B,
               int Kp, int Nt, int Mreal, float* __restrict__ C, long long ldc,
               const float* __restrict__ bias)
{
  __shared__ __align__(16) u16 As[2][4096];
  __shared__ __align__(16) u16 Bs[2][4096];
  const int tid  = threadIdx.x;
  const int lane = tid & 63;
  const int wr   = (tid >> 6) >> 1, wc = (tid >> 6) & 1;
  const int l4   = lane >> 4, l15 = lane & 15;
  const int mt   = blockIdx.x / Nt, nt = blockIdx.x % Nt;

  const size_t arow = (size_t)(mt*128 + (tid>>2)) * Kp + (tid&3)*8;
  const size_t brow = (size_t)(nt*128 + (tid>>2)) * Kp + (tid&3)*8;
  const int    ldst = (tid>>2)*32 + (tid&3)*8;
  const size_t rowskip = (size_t)64 * Kp;

  f32x4 acc[4][4];
  #pragma unroll
  for (int i=0;i<4;i++)
    #pragma unroll
    for (int j=0;j<4;j++) acc[i][j] = f32x4{0.f,0.f,0.f,0.f};

  const int NT = Kp >> 5;
  {
    const u16* a0 = A + arow; const u16* b0 = B + brow;
    GLD16(a0,           &As[0][ldst]);
    GLD16(a0 + rowskip, &As[0][ldst + 2048]);
    GLD16(b0,           &Bs[0][ldst]);
    GLD16(b0 + rowskip, &Bs[0][ldst + 2048]);
  }
  __syncthreads();

  for (int kt=0; kt<NT; ++kt){
    const int cur = kt & 1;
    if (kt + 1 < NT){
      const u16* a0 = A + arow + (size_t)(kt+1)*32;
      const u16* b0 = B + brow + (size_t)(kt+1)*32;
      GLD16(a0,           &As[cur^1][ldst]);
      GLD16(a0 + rowskip, &As[cur^1][ldst + 2048]);
      GLD16(b0,           &Bs[cur^1][ldst]);
      GLD16(b0 + rowskip, &Bs[cur^1][ldst + 2048]);
    }
    bf16x8 af[4], bf[4];
    #pragma unroll
    for (int mi=0;mi<4;mi++)
      af[mi] = *(const bf16x8*)&As[cur][(wr*64 + mi*16 + l15)*32 + l4*8];
    #pragma unroll
    for (int ni=0;ni<4;ni++)
      bf[ni] = *(const bf16x8*)&Bs[cur][(wc*64 + ni*16 + l15)*32 + l4*8];
    #pragma unroll
    for (int mi=0;mi<4;mi++)
      #pragma unroll
      for (int ni=0;ni<4;ni++)
        acc[mi][ni] = __builtin_amdgcn_mfma_f32_16x16x32_bf16(af[mi], bf[ni], acc[mi][ni], 0, 0, 0);
    __syncthreads();
  }

  const int ob0 = mt*128 + wr*64;
  const int nb0 = nt*128 + wc*64;
  #pragma unroll
  for (int mi=0;mi<4;mi++)
    #pragma unroll
    for (int r=0;r<4;r++){
      const int o = ob0 + mi*16 + l4*4 + r;
      if (o < Mreal){
        const float bb = bias[o];
        #pragma unroll
        for (int ni=0;ni<4;ni++){
          const int n = nb0 + ni*16 + l15;
          C[(size_t)o*ldc + n] = acc[mi][ni][r] + bb;
        }
      }
    }
}

// --- f32 -> bf16 padded convert (ctw only) ----------------------------------
__global__ void k_cvt_pad(const float* __restrict__ src, int srows, int scols,
                          int lds_, int koff, u16* __restrict__ dst, int Kp)
{
  const int r = blockIdx.x;
  const int nch = Kp >> 3;
  for (int ch = threadIdx.x; ch < nch; ch += blockDim.x){
    const int k = ch*8;
    u16 o[8];
    if (r < srows){
      #pragma unroll
      for (int i=0;i<8;i++){
        const int kk = k + i;
        o[i] = (kk < scols) ? f2bf(src[(size_t)r*lds_ + koff + kk]) : (u16)0;
      }
    } else {
      #pragma unroll
      for (int i=0;i<8;i++) o[i] = 0;
    }
    u16x8 vv = { o[0],o[1],o[2],o[3],o[4],o[5],o[6],o[7] };
    *(u16x8*)&dst[(size_t)r*Kp + k] = vv;
  }
}

// --- objB: rows 0..639 = bf16(obj), 640..1279 = bf16(|obj|), K pad 4480 -----
__global__ void k_cvt_obj(const float* __restrict__ obj, u16* __restrict__ dst)
{
  const int r = blockIdx.x;
  const int ab = (r >= 640);
  const float* src = obj + (size_t)(ab ? r-640 : r)*4424;
  for (int ch = threadIdx.x; ch < 560; ch += 256){
    const int k = ch*8;
    u16 o[8];
    #pragma unroll
    for (int i=0;i<8;i++){
      const int kk = k+i;
      float f = (kk < 4424) ? src[kk] : 0.f;
      if (ab) f = fabsf(f);
      o[i] = f2bf(f);
    }
    u16x8 vv = { o[0],o[1],o[2],o[3],o[4],o[5],o[6],o[7] };
    *(u16x8*)&dst[(size_t)r*4480 + k] = vv;
  }
}

// --- x (B,256,1024) -> xT bf16 [(b*1024+s)][c] ------------------------------
__global__ void k_xT(const float* __restrict__ x, u16* __restrict__ xT)
{
  __shared__ float t[32][33];
  const int bid = blockIdx.x;
  const int b = bid >> 8; const int cs = (bid >> 5) & 7; const int ss = bid & 31;
  const int tx = threadIdx.x & 31, ty = threadIdx.x >> 5;
  #pragma unroll
  for (int i=0;i<4;i++){
    const int r = ty + i*8;
    t[r][tx] = x[((size_t)(b*256 + cs*32 + r))*1024 + ss*32 + tx];
  }
  __syncthreads();
  #pragma unroll
  for (int i=0;i<4;i++){
    const int r = ty + i*8;
    xT[((size_t)(b*1024 + ss*32 + r))*256 + cs*32 + tx] = f2bf(t[tx][r]);
  }
}

// --- y = fc_w@xr ; mask = sigmoid(y) ----------------------------------------
__global__ void k_ymask(const float* __restrict__ x, const float* __restrict__ fcw,
                        float* __restrict__ y, float* __restrict__ mask)
{
  __shared__ float fc[1024];
  const int b = blockIdx.x >> 2, st = blockIdx.x & 3;
  for (int i=threadIdx.x; i<1024; i+=256) fc[i] = fcw[i];
  __syncthreads();
  const int s = st*256 + threadIdx.x;
  float a0=0,a1=0,a2=0,a3=0;
  for (int c=0;c<256;c++){
    const float xv = x[((size_t)(b*256+c))*1024 + s];
    a0 += fc[c]*xv; a1 += fc[256+c]*xv; a2 += fc[512+c]*xv; a3 += fc[768+c]*xv;
  }
  const size_t base = (size_t)(b*4)*1024 + s;
  y[base]        = a0; mask[base]        = 1.f/(1.f+expf(-a0));
  y[base+1024]   = a1; mask[base+1024]   = 1.f/(1.f+expf(-a1));
  y[base+2048]   = a2; mask[base+2048]   = 1.f/(1.f+expf(-a2));
  y[base+3072]   = a3; mask[base+3072]   = 1.f/(1.f+expf(-a3));
}

__global__ void k_out1(const float* __restrict__ y, float* __restrict__ out1){
  const int bn = blockIdx.x;
  float m = -3.4e38f;
  for (int s=threadIdx.x; s<1024; s+=256) m = fmaxf(m, y[(size_t)bn*1024+s]);
  for (int o=32;o;o>>=1) m = fmaxf(m, __shfl_xor(m,o));
  __shared__ float red[4];
  if ((threadIdx.x&63)==0) red[threadIdx.x>>6] = m;
  __syncthreads();
  if (threadIdx.x==0) out1[bn] = fmaxf(fmaxf(red[0],red[1]),fmaxf(red[2],red[3]));
}

// --- v[b,j,m] = sum_s vpreT[j][b*1024+s]*mask[b,m,s] ------------------------
__global__ void k_v(const float* __restrict__ vpreT, const float* __restrict__ mask,
                    float* __restrict__ v){
  const int b = blockIdx.x >> 7, j = blockIdx.x & 127;
  float a[4]={0,0,0,0};
  for (int s=threadIdx.x; s<1024; s+=256){
    const float pv = vpreT[(size_t)j*8192 + b*1024 + s];
    #pragma unroll
    for (int m=0;m<4;m++) a[m] += pv * mask[((size_t)(b*4+m))*1024 + s];
  }
  __shared__ float red[4][5];
  #pragma unroll
  for (int m=0;m<4;m++){
    float t=a[m];
    for (int o=32;o;o>>=1) t += __shfl_xor(t,o);
    if ((threadIdx.x&63)==0) red[m][threadIdx.x>>6]=t;
  }
  __syncthreads();
  if (threadIdx.x<4)
    v[(size_t)(b*128+j)*4 + threadIdx.x] =
      red[threadIdx.x][0]+red[threadIdx.x][1]+red[threadIdx.x][2]+red[threadIdx.x][3];
}

// --- lv[b,j,n] = leaky(sum_m A[n,m]*v[b,j,m]) -------------------------------
__global__ void k_lv(const float* __restrict__ Am, const float* __restrict__ v,
                     float* __restrict__ lv){
  const int idx = blockIdx.x*256 + threadIdx.x;
  if (idx < 1024){
    #pragma unroll
    for (int n=0;n<4;n++){
      float s=0;
      #pragma unroll
      for (int m=0;m<4;m++) s += Am[n*4+m]*v[idx*4+m];
      lv[idx*4+n] = lky(s);
    }
  }
}

// --- sV[b,o,n] = sum_j sw_w[o,8848+j]*lv[b,j,n] -----------------------------
__global__ void k_sV(const float* __restrict__ sw, const float* __restrict__ lv,
                     float* __restrict__ sV){
  __shared__ float l[4096];
  for (int i=threadIdx.x; i<4096; i+=256) l[i]=lv[i];
  __syncthreads();
  const int o = blockIdx.x*256 + threadIdx.x;
  if (o >= 8976) return;
  float acc[8][4] = {};
  const float* row = sw + (size_t)o*8976 + 8848;
  for (int j=0;j<128;j++){
    const float wv = row[j];
    #pragma unroll
    for (int b=0;b<8;b++){
      const float* lb = &l[(b*128+j)*4];
      #pragma unroll
      for (int n=0;n<4;n++) acc[b][n] += wv*lb[n];
    }
  }
  #pragma unroll
  for (int b=0;b<8;b++){
    f32x4 vv = {acc[b][0],acc[b][1],acc[b][2],acc[b][3]};
    *(f32x4*)&sV[((size_t)b*8976 + o)*4] = vv;
  }
}

// --- BN fold ----------------------------------------------------------------
__global__ void k_so(const float* __restrict__ cgb, const float* __restrict__ g,
                     const float* __restrict__ b2, const float* __restrict__ m,
                     const float* __restrict__ vvar, float* __restrict__ so){
  const int o = blockIdx.x*256+threadIdx.x;
  if (o<8976){
    const float sc = g[o]*rsqrtf(vvar[o]+1e-5f);
    so[o]=sc; so[8976+o] = (cgb[o]-m[o])*sc + b2[o];
  }
}

// --- glbB (bf16 mean_n hg, K pad 9088) + t2[q,o',n] = sum_c co_w2[o',c]*hg --
__global__ void k_glb_t2(const float* __restrict__ U, const float* __restrict__ obj,
                         const int* __restrict__ rel,
                         const float* __restrict__ sV, const float* __restrict__ swb,
                         const float* __restrict__ v, const float* __restrict__ Am,
                         const float* __restrict__ cow, u16* __restrict__ glbB,
                         float* __restrict__ t2)
{
  const int q = blockIdx.x; const int b = q >> 7;
  const int i1 = rel[q*2], i2 = rel[q*2+1];
  const float* u1  = U + (size_t)i1*17952;
  const float* u2  = U + (size_t)i2*17952 + 8976;
  const float* u1a = U + (size_t)(640+i1)*17952;
  const float* u2a = U + (size_t)(640+i2)*17952 + 8976;
  const float* o1 = obj + (size_t)i1*4424;
  const float* o2 = obj + (size_t)i2*4424;
  float rA[4], aA[4];
  #pragma unroll
  for (int n=0;n<4;n++){
    const float s = Am[n*4]+Am[n*4+1]+Am[n*4+2]+Am[n*4+3];
    rA[n]=0.6f*s; aA[n]=0.4f*fabsf(s);
  }
  float t2a[16] = {};
  for (int c = threadIdx.x; c < 9088; c += 256){
    if (c < 8976){
      const float p1 = u1[c] + u2[c];
      const float p2 = u1a[c] + u2a[c];
      const f32x4 sv = *(const f32x4*)&sV[((size_t)b*8976 + c)*4];
      const float sb = swb[c];
      const float gs = (c < 4424) ? o1[c] : (c < 8848) ? o2[c-4424] : 0.f;
      float hg[4]; float sum = 0.f;
      #pragma unroll
      for (int n=0;n<4;n++){
        const float xs2 = lky(rA[n]*p1 + aA[n]*p2 + sv[n] + sb);
        const float g = (c < 8848) ? gs : v[((size_t)b*128 + (c-8848))*4 + n];
        hg[n] = g + xs2; sum += hg[n];
      }
      glbB[(size_t)q*9088 + c] = f2bf(0.25f*sum);
      #pragma unroll
      for (int o4=0;o4<4;o4++){
        const float cw = cow[(size_t)o4*17952 + 8976 + c];
        #pragma unroll
        for (int n=0;n<4;n++) t2a[o4*4+n] += cw*hg[n];
      }
    } else {
      glbB[(size_t)q*9088 + c] = 0;
    }
  }
  __shared__ float red[16][5];
  #pragma unroll
  for (int i=0;i<16;i++){
    float t = t2a[i];
    for (int o=32;o;o>>=1) t += __shfl_xor(t,o);
    if ((threadIdx.x&63)==0) red[i][threadIdx.x>>6]=t;
  }
  __syncthreads();
  if (threadIdx.x < 16)
    t2[q*16+threadIdx.x] = red[threadIdx.x][0]+red[threadIdx.x][1]
                          +red[threadIdx.x][2]+red[threadIdx.x][3];
}

// --- hd with inline adj: aj = sigmoid(co1acc[q][a] + t2[q][a,m] + cob[a]) ---
__global__ void k_hd(const float* __restrict__ U, const float* __restrict__ obj,
                     const int* __restrict__ rel,
                     const float* __restrict__ sV, const float* __restrict__ swb,
                     const float* __restrict__ v, const float* __restrict__ Am,
                     const float* __restrict__ co1acc, const float* __restrict__ t2,
                     const float* __restrict__ cob, u16* __restrict__ hdb)
{
  const int q = blockIdx.x; const int b = q>>7;
  const int i1 = rel[q*2], i2 = rel[q*2+1];
  const float* u1  = U + (size_t)i1*17952;
  const float* u2  = U + (size_t)i2*17952 + 8976;
  const float* u1a = U + (size_t)(640+i1)*17952;
  const float* u2a = U + (size_t)(640+i2)*17952 + 8976;
  const float* o1 = obj + (size_t)i1*4424;
  const float* o2 = obj + (size_t)i2*4424;
  float rA[4], aA[4];
  #pragma unroll
  for (int n=0;n<4;n++){
    const float s = Am[n*4]+Am[n*4+1]+Am[n*4+2]+Am[n*4+3];
    rA[n]=0.6f*s; aA[n]=0.4f*fabsf(s);
  }
  __shared__ float aj[16];
  if (threadIdx.x<16){
    const int a_=threadIdx.x>>2, m=threadIdx.x&3;
    const float tt = co1acc[q*4+a_] + t2[q*16 + a_*4 + m] + cob[a_];
    aj[threadIdx.x] = 1.f/(1.f+expf(-tt));
  }
  __syncthreads();
  float ajr[16];
  #pragma unroll
  for (int i=0;i<16;i++) ajr[i]=aj[i];
  for (int c=threadIdx.x; c<9088; c+=256){
    if (c<8976){
      const float p1 = u1[c] + u2[c];
      const float p2 = u1a[c] + u2a[c];
      const f32x4 sv = *(const f32x4*)&sV[((size_t)b*8976 + c)*4];
      const float sb = swb[c];
      const float gs = (c < 4424) ? o1[c] : (c < 8848) ? o2[c-4424] : 0.f;
      float hg[4];
      #pragma unroll
      for (int n=0;n<4;n++){
        const float xs2 = lky(rA[n]*p1 + aA[n]*p2 + sv[n] + sb);
        const float g = (c < 8848) ? gs : v[((size_t)b*128 + (c-8848))*4 + n];
        hg[n] = g + xs2;
      }
      #pragma unroll
      for (int m=0;m<4;m++){
        const float hv = lky(hg[0]*ajr[m] + hg[1]*ajr[4+m] + hg[2]*ajr[8+m] + hg[3]*ajr[12+m]);
        hdb[((size_t)(q*4+m))*9088 + c] = f2bf(hv);
      }
    } else {
      #pragma unroll
      for (int m=0;m<4;m++) hdb[((size_t)(q*4+m))*9088 + c] = 0;
    }
  }
}

// --- final ------------------------------------------------------------------
__global__ void k_final(const float* __restrict__ o2f, const float* __restrict__ out1,
                        const float* __restrict__ llb, const float* __restrict__ mm,
                        float* __restrict__ out)
{
  const int idx = blockIdx.x*256+threadIdx.x;
  if (idx < 4096){
    const int q = idx>>2, o = idx&3, b = q>>7;
    float s=0.f;
    #pragma unroll
    for (int m=0;m<4;m++) s += lky(o2f[(q*4+o)*4+m] + llb[o]) * mm[o*4+m];
    out[idx] = 0.5f*(out1[b*4+o] + s);
  }
}

extern "C" void kernel_launch(void* const* d_in, const int* in_sizes, int n_in,
                              void* d_out, int out_size, void* d_ws, size_t ws_size,
                              hipStream_t stream)
{
  const float* x    = (const float*)d_in[0];
  const int*   rel  = (const int*)d_in[1];
  const float* obj  = (const float*)d_in[2];
  const float* fcw  = (const float*)d_in[3];
  const float* ctw  = (const float*)d_in[4];
  const float* ctb  = (const float*)d_in[5];
  const float* Am   = (const float*)d_in[6];
  const float* sww  = (const float*)d_in[7];
  const float* swb  = (const float*)d_in[8];
  const float* cgw  = (const float*)d_in[9];
  const float* cgb  = (const float*)d_in[10];
  const float* bng  = (const float*)d_in[11];
  const float* bnb  = (const float*)d_in[12];
  const float* bnm  = (const float*)d_in[13];
  const float* bnv  = (const float*)d_in[14];
  const float* cow  = (const float*)d_in[15];
  const float* cob  = (const float*)d_in[16];
  const float* dww  = (const float*)d_in[17];
  const float* dwb  = (const float*)d_in[18];
  const float* llw  = (const float*)d_in[19];
  const float* llb  = (const float*)d_in[20];
  const float* mm   = (const float*)d_in[21];
  float* out = (float*)d_out;
  (void)in_sizes; (void)n_in; (void)out_size; (void)ws_size;

  char* ws = (char*)d_ws;
  size_t off = 0;
  auto alloc = [&](size_t bytes)->char*{
    char* p = ws + off; off = (off + bytes + 255) & ~(size_t)255; return p;
  };
  float* U     = (float*)alloc((size_t)1280*17952*4);
  u16*   glbB  = (u16*)  alloc((size_t)1024*9088*2);
  u16*   hdb   = (u16*)  alloc((size_t)4096*9088*2);
  u16*   objB  = (u16*)  alloc((size_t)1280*4480*2);
  float* glb2  = (float*)alloc((size_t)1024*8976*4);
  u16*   xT    = (u16*)  alloc((size_t)8192*256*2);
  u16*   ctwb  = (u16*)  alloc((size_t)128*256*2);
  float* y     = (float*)alloc((size_t)32768*4);
  float* mask  = (float*)alloc((size_t)32768*4);
  float* out1  = (float*)alloc((size_t)32*4);
  float* vpreT = (float*)alloc((size_t)128*8192*4);
  float* v     = (float*)alloc((size_t)4096*4);
  float* lv    = (float*)alloc((size_t)4096*4);
  float* sV    = (float*)alloc((size_t)287232*4);
  float* so    = (float*)alloc((size_t)2*8976*4);
  float* t2    = (float*)alloc((size_t)16384*4);
  float* co1a  = (float*)alloc((size_t)4096*4);
  float* o2f   = (float*)alloc((size_t)16384*4);

  // stage 1: small precomputes
  k_xT<<<dim3(2048), dim3(256), 0, stream>>>(x, xT);
  k_cvt_pad<<<dim3(128), dim3(256), 0, stream>>>(ctw, 128, 256, 256, 0, ctwb, 256);
  k_ymask<<<dim3(32), dim3(256), 0, stream>>>(x, fcw, y, mask);
  k_out1<<<dim3(32), dim3(256), 0, stream>>>(y, out1);
  gemm_vpre<<<dim3(64), dim3(256), 0, stream>>>(
      ctwb, xT, 256, 64, 128, vpreT, (long long)8192, ctb);
  k_v<<<dim3(1024), dim3(256), 0, stream>>>(vpreT, mask, v);

  // stage 2: U = [W_F_left; W_F_right] @ [obj; |obj|]^T
  //          A = sww f32 direct (STACKED), Kp 4480, NT=70
  k_cvt_obj<<<dim3(1280), dim3(256), 0, stream>>>(obj, objB);
  gemmV<0,1><<<dim3(71*5), dim3(1024), 0, stream>>>(
      sww, 8976, 4424, 17952, objB, 4480, 5, 5, 17952, U, (long long)17952,
      nullptr, nullptr, nullptr, nullptr, nullptr);

  // stage 3: sV, glb, t2
  k_lv<<<dim3(4), dim3(256), 0, stream>>>(Am, v, lv);
  k_sV<<<dim3(36), dim3(256), 0, stream>>>(sww, lv, sV);
  k_glb_t2<<<dim3(1024), dim3(256), 0, stream>>>(U, obj, rel, sV, swb, v, Am,
                                                 cow, glbB, t2);

  // stage 4: GEMM2 (A = cgw f32 direct, Kp 9088, NT=142) + fused co1
  k_so<<<dim3(36), dim3(256), 0, stream>>>(cgb, bng, bnb, bnm, bnv, so);
  hipMemsetAsync(co1a, 0, (size_t)4096*4, stream);
  gemmV<2,0><<<dim3(36*4), dim3(1024), 0, stream>>>(
      cgw, 8976, 8976, 8976, glbB, 9088, 4, 4, 8976, glb2, (long long)8976,
      nullptr, so, so + 8976, cow, co1a);

  // stage 5: hd (adj inline from co1a + t2 + cob)
  k_hd<<<dim3(1024), dim3(256), 0, stream>>>(U, obj, rel, sV, swb, v, Am,
                                             co1a, t2, cob, hdb);

  // stage 6: GEMM3 (A = dww f32 direct, Kp 9088, SN=8) fused diagonal ll_w
  hipMemsetAsync(o2f, 0, (size_t)16384*4, stream);
  gemmV<3,0><<<dim3(36*16), dim3(1024), 0, stream>>>(
      dww, 8976, 8976, 8976, hdb, 9088, 16, 8, 8976, nullptr, 0,
      dwb, nullptr, nullptr, llw, o2f);

  // stage 7: final combine
  k_final<<<dim3(16), dim3(256), 0, stream>>>(o2f, out1, llb, mm, out);
}

// Round 14
// 1989.943 us; speedup vs baseline: 2.6534x; 2.6534x over previous
//
#include <hip/hip_runtime.h>
#include <stdint.h>

#define DEVI __device__ __forceinline__

typedef unsigned short u16;
typedef __bf16 bf16x8 __attribute__((ext_vector_type(8)));
typedef float f32x4 __attribute__((ext_vector_type(4)));
typedef u16 u16x8 __attribute__((ext_vector_type(8)));

DEVI u16 f2bf(float f){
  union { float f; unsigned u; } v; v.f = f;
  unsigned r = v.u + 0x7FFFu + ((v.u >> 16) & 1u);
  return (u16)(r >> 16);
}
DEVI float bf2f(u16 h){
  union { unsigned u; float f; } v; v.u = ((unsigned)h) << 16;
  return v.f;
}
DEVI float lky(float t){ return t > 0.f ? t : 0.2f * t; }

#define GLD16(gp, lp) __builtin_amdgcn_global_load_lds( \
    (const __attribute__((address_space(1))) void*)(gp), \
    (__attribute__((address_space(3))) void*)(lp), 16, 0, 0)

// ===========================================================================
// gemmU (R12 measured best: total 1993us, GEMM3 751us, MfmaUtil 40%):
// 256x256 tile, BK=64, 16 waves (4x4), wave tile 64x64 (min-LDS-read shape),
// acc 64 VGPR -> 4 waves/SIMD, conflict-free slot^(row&7) swizzle, 128KB
// dbuf, one barrier-pair per 64-K tile.
// CLOSED paths (measured): smaller tiles (R7/R10: traffic/conflicts),
// deeper prefetch (R8), lgkm relaxation (R6), streamer fusion (R6),
// f32-direct-A (R3: register spill; R13: 322MB f32 weights exceed L3 ->
// 6GB HBM traffic; bf16 copy IS the L3-residency optimization).
// EPI 0: C=acc | EPI 2: leaky(acc*scale+off) + fused co1 | EPI 3: diag llw.
// ===========================================================================
template<int EPI>
__global__ __launch_bounds__(1024, 4)
void gemmU(const u16* __restrict__ A, const u16* __restrict__ B,
           int Kp, int Nt, int SN, int Mreal, float* __restrict__ C, long long ldc,
           const float* __restrict__ bias, const float* __restrict__ scale,
           const float* __restrict__ off, const float* __restrict__ llw,
           float* __restrict__ oacc)
{
  __shared__ __align__(16) u16 As[2][16384];   // 256 rows x 64 cols
  __shared__ __align__(16) u16 Bs[2][16384];
  const int t    = threadIdx.x;                // 0..1023
  const int lane = t & 63;
  const int wid  = t >> 6;                     // 0..15
  const int wr = wid >> 2, wc = wid & 3;       // 4 x 4 waves
  const int l4 = lane >> 4, l15 = lane & 15;

  // bijective XCD swizzle (m204 variant)
  const int nwg = gridDim.x;
  const int xc = blockIdx.x & 7, pp = blockIdx.x >> 3;
  const int qq = nwg >> 3, rr = nwg & 7;
  const int wg = (xc < rr ? xc*(qq+1) : rr*(qq+1) + (xc-rr)*qq) + pp;
  // supertile: strips of SN nt-columns, mt-major inside a strip
  const int strip_sz = (nwg / Nt) * SN;
  const int strip = wg / strip_sz, srem = wg % strip_sz;
  const int mt = srem / SN, nt = strip*SN + srem % SN;

  const size_t am0 = (size_t)mt*256;
  const size_t bn0 = (size_t)nt*256;

  f32x4 acc[4][4];
  #pragma unroll
  for (int i = 0; i < 4; ++i)
    #pragma unroll
    for (int j = 0; j < 4; ++j) acc[i][j] = f32x4{0.f,0.f,0.f,0.f};
  bf16x8 afr[4], bfr[4];

  const int NT = Kp >> 6;                      // 64-wide K tiles (even)

  // staging: 1024 threads x 2 sweeps cover 2048 x 16B = 256 rows x 64 cols.
  // linear LDS dest + pre-swizzled global col (slot ^ (row&7)) [both-sides].
  const int srl0 = t >> 3, ssl = t & 7;        // sweep j adds 128 rows
  const u16* pA = A + (am0 + srl0)*(size_t)Kp;
  const u16* pB = B + (bn0 + srl0)*(size_t)Kp;
  const size_t rowskip = (size_t)128 * Kp;
  const int sco0 = ((ssl ^ (srl0 & 7))*8);
  const int sco1 = ((ssl ^ ((srl0+128) & 7))*8);

  // frag read offsets (u16 units); XOR distributes over *8 (slot < 8):
  // offset = base ^ ((ks*4+l4)*8)
  int aoff[4], boff[4];
  #pragma unroll
  for (int mi = 0; mi < 4; ++mi){
    const int r = wr*64 + mi*16 + l15;
    aoff[mi] = r*64 + ((r & 7)*8);
  }
  #pragma unroll
  for (int ni = 0; ni < 4; ++ni){
    const int r = wc*64 + ni*16 + l15;
    boff[ni] = r*64 + ((r & 7)*8);
  }

  auto STAGE = [&](int kc, int buf){
    u16* la = &As[buf][0]; u16* lb = &Bs[buf][0];
    GLD16(pA + kc + sco0,           la + t*8);
    GLD16(pA + rowskip + kc + sco1, la + 8192 + t*8);
    GLD16(pB + kc + sco0,           lb + t*8);
    GLD16(pB + rowskip + kc + sco1, lb + 8192 + t*8);
  };

  // prologue: tile0 -> buf0
  STAGE(0, 0);
  asm volatile("s_waitcnt vmcnt(0)" ::: "memory");
  __builtin_amdgcn_s_barrier();

  #define GU_BODY(KT, RB_, WB_)                                              \
  {                                                                          \
    const int nx = ((KT)+1 < NT) ? (KT)+1 : NT-1;                            \
    STAGE(nx*64, WB_);                                                       \
    const u16* ab = &As[RB_][0];                                             \
    const u16* bb = &Bs[RB_][0];                                             \
    _Pragma("unroll")                                                        \
    for (int ks = 0; ks < 2; ++ks){                                          \
      const int sx = (ks*4 + l4)*8;                                          \
      _Pragma("unroll")                                                      \
      for (int mi = 0; mi < 4; ++mi)                                         \
        afr[mi] = *(const bf16x8*)&ab[aoff[mi] ^ sx];                        \
      _Pragma("unroll")                                                      \
      for (int ni = 0; ni < 4; ++ni)                                         \
        bfr[ni] = *(const bf16x8*)&bb[boff[ni] ^ sx];                        \
      __builtin_amdgcn_s_setprio(1);                                         \
      _Pragma("unroll")                                                      \
      for (int mi = 0; mi < 4; ++mi)                                         \
        _Pragma("unroll")                                                    \
        for (int ni = 0; ni < 4; ++ni)                                       \
          acc[mi][ni] = __builtin_amdgcn_mfma_f32_16x16x32_bf16(             \
              afr[mi], bfr[ni], acc[mi][ni], 0, 0, 0);                       \
      __builtin_amdgcn_s_setprio(0);                                         \
    }                                                                        \
    asm volatile("s_waitcnt vmcnt(0)" ::: "memory");                         \
    __builtin_amdgcn_s_barrier();                                            \
  }

  for (int kt = 0; kt < NT; kt += 2){
    GU_BODY(kt,   0, 1);
    GU_BODY(kt+1, 1, 0);
  }
  #undef GU_BODY

  const int ob0 = mt*256 + wr*64;
  const int nb0 = nt*256 + wc*64;

  if (EPI == 0){
    #pragma unroll
    for (int mi = 0; mi < 4; ++mi){
      const int ob = ob0 + mi*16 + l4*4;
      if (ob < Mreal){
        #pragma unroll
        for (int ni = 0; ni < 4; ++ni){
          const int n = nb0 + ni*16 + l15;
          *(f32x4*)&C[(size_t)n*ldc + ob] = acc[mi][ni];
        }
      }
    }
  } else if (EPI == 2){
    // glb2 store + fused co1[n][a] += sum_c cow[a][c]*glb2[n][c] partials
    #pragma unroll
    for (int ni = 0; ni < 4; ++ni){
      const int n = nb0 + ni*16 + l15;
      float sa0=0.f, sa1=0.f, sa2=0.f, sa3=0.f;
      #pragma unroll
      for (int mi = 0; mi < 4; ++mi){
        const int ob = ob0 + mi*16 + l4*4;
        if (ob < Mreal){
          const float sc0=scale[ob],sc1=scale[ob+1],sc2=scale[ob+2],sc3=scale[ob+3];
          const float of0=off[ob],of1=off[ob+1],of2=off[ob+2],of3=off[ob+3];
          f32x4 a = acc[mi][ni];
          f32x4 vv = { lky(a[0]*sc0+of0), lky(a[1]*sc1+of1),
                       lky(a[2]*sc2+of2), lky(a[3]*sc3+of3) };
          *(f32x4*)&C[(size_t)n*ldc + ob] = vv;
          #pragma unroll
          for (int r = 0; r < 4; ++r){
            const float vr = vv[r];
            sa0 += llw[(size_t)0*17952 + ob + r] * vr;   // llw == cow here
            sa1 += llw[(size_t)1*17952 + ob + r] * vr;
            sa2 += llw[(size_t)2*17952 + ob + r] * vr;
            sa3 += llw[(size_t)3*17952 + ob + r] * vr;
          }
        }
      }
      float sv[4] = {sa0,sa1,sa2,sa3};
      #pragma unroll
      for (int a4 = 0; a4 < 4; ++a4){
        float tt = sv[a4];
        tt += __shfl_xor(tt, 16);
        tt += __shfl_xor(tt, 32);
        if (l4 == 0) atomicAdd(&oacc[n*4 + a4], tt);     // oacc == co1acc
      }
    }
  } else { // EPI == 3: diagonal-only (mask_mat = eye)
    #pragma unroll
    for (int ni = 0; ni < 4; ++ni){
      const int n = nb0 + ni*16 + l15;
      const int m = n & 3, q = n >> 2;
      float s = 0.f;
      #pragma unroll
      for (int mi = 0; mi < 4; ++mi){
        #pragma unroll
        for (int r = 0; r < 4; ++r){
          const int o = ob0 + mi*16 + l4*4 + r;
          if (o < Mreal){
            const float val = lky(acc[mi][ni][r] + bias[o]);
            s += llw[(size_t)m*8976 + o] * val;
          }
        }
      }
      s += __shfl_xor(s, 16);
      s += __shfl_xor(s, 32);
      if (l4 == 0) atomicAdd(&oacc[(q*4 + m)*4 + m], s);
    }
  }
}

// --- small 128x128 GEMM for v_pre (C[o][n]+bias) -----------------------------
__global__ __launch_bounds__(256)
void gemm_vpre(const u16* __restrict__ A, const u16* __restrict__ B,
               int Kp, int Nt, int Mreal, float* __restrict__ C, long long ldc,
               const float* __restrict__ bias)
{
  __shared__ __align__(16) u16 As[2][4096];
  __shared__ __align__(16) u16 Bs[2][4096];
  const int tid  = threadIdx.x;
  const int lane = tid & 63;
  const int wr   = (tid >> 6) >> 1, wc = (tid >> 6) & 1;
  const int l4   = lane >> 4, l15 = lane & 15;
  const int mt   = blockIdx.x / Nt, nt = blockIdx.x % Nt;

  const size_t arow = (size_t)(mt*128 + (tid>>2)) * Kp + (tid&3)*8;
  const size_t brow = (size_t)(nt*128 + (tid>>2)) * Kp + (tid&3)*8;
  const int    ldst = (tid>>2)*32 + (tid&3)*8;
  const size_t rowskip = (size_t)64 * Kp;

  f32x4 acc[4][4];
  #pragma unroll
  for (int i=0;i<4;i++)
    #pragma unroll
    for (int j=0;j<4;j++) acc[i][j] = f32x4{0.f,0.f,0.f,0.f};

  const int NT = Kp >> 5;
  {
    const u16* a0 = A + arow; const u16* b0 = B + brow;
    GLD16(a0,           &As[0][ldst]);
    GLD16(a0 + rowskip, &As[0][ldst + 2048]);
    GLD16(b0,           &Bs[0][ldst]);
    GLD16(b0 + rowskip, &Bs[0][ldst + 2048]);
  }
  __syncthreads();

  for (int kt=0; kt<NT; ++kt){
    const int cur = kt & 1;
    if (kt + 1 < NT){
      const u16* a0 = A + arow + (size_t)(kt+1)*32;
      const u16* b0 = B + brow + (size_t)(kt+1)*32;
      GLD16(a0,           &As[cur^1][ldst]);
      GLD16(a0 + rowskip, &As[cur^1][ldst + 2048]);
      GLD16(b0,           &Bs[cur^1][ldst]);
      GLD16(b0 + rowskip, &Bs[cur^1][ldst + 2048]);
    }
    bf16x8 af[4], bf[4];
    #pragma unroll
    for (int mi=0;mi<4;mi++)
      af[mi] = *(const bf16x8*)&As[cur][(wr*64 + mi*16 + l15)*32 + l4*8];
    #pragma unroll
    for (int ni=0;ni<4;ni++)
      bf[ni] = *(const bf16x8*)&Bs[cur][(wc*64 + ni*16 + l15)*32 + l4*8];
    #pragma unroll
    for (int mi=0;mi<4;mi++)
      #pragma unroll
      for (int ni=0;ni<4;ni++)
        acc[mi][ni] = __builtin_amdgcn_mfma_f32_16x16x32_bf16(af[mi], bf[ni], acc[mi][ni], 0, 0, 0);
    __syncthreads();
  }

  const int ob0 = mt*128 + wr*64;
  const int nb0 = nt*128 + wc*64;
  #pragma unroll
  for (int mi=0;mi<4;mi++)
    #pragma unroll
    for (int r=0;r<4;r++){
      const int o = ob0 + mi*16 + l4*4 + r;
      if (o < Mreal){
        const float bb = bias[o];
        #pragma unroll
        for (int ni=0;ni<4;ni++){
          const int n = nb0 + ni*16 + l15;
          C[(size_t)o*ldc + n] = acc[mi][ni][r] + bb;
        }
      }
    }
}

// --- f32 -> bf16 padded convert ---------------------------------------------
__global__ void k_cvt_pad(const float* __restrict__ src, int srows, int scols,
                          int lds_, int koff, u16* __restrict__ dst, int Kp)
{
  const int r = blockIdx.x;
  const int nch = Kp >> 3;
  for (int ch = threadIdx.x; ch < nch; ch += blockDim.x){
    const int k = ch*8;
    u16 o[8];
    if (r < srows){
      #pragma unroll
      for (int i=0;i<8;i++){
        const int kk = k + i;
        o[i] = (kk < scols) ? f2bf(src[(size_t)r*lds_ + koff + kk]) : (u16)0;
      }
    } else {
      #pragma unroll
      for (int i=0;i<8;i++) o[i] = 0;
    }
    u16x8 vv = { o[0],o[1],o[2],o[3],o[4],o[5],o[6],o[7] };
    *(u16x8*)&dst[(size_t)r*Kp + k] = vv;
  }
}

// --- single-pass dual-write sww cvt (reads sww once) ------------------------
__global__ void k_cvt_sww(const float* __restrict__ src, u16* __restrict__ dst)
{
  const int r = blockIdx.x;                    // 0..8975
  const float* row = src + (size_t)r*8976;
  u16* d1 = dst + (size_t)r*4480;
  u16* d2 = dst + (size_t)(8976+r)*4480;
  for (int ch = threadIdx.x; ch < 560; ch += 256){
    const int k = ch*8;
    u16 a[8], b[8];
    #pragma unroll
    for (int i=0;i<8;i++){
      const int kk = k+i;
      a[i] = (kk < 4424) ? f2bf(row[kk])        : (u16)0;
      b[i] = (kk < 4424) ? f2bf(row[4424 + kk]) : (u16)0;
    }
    u16x8 va = { a[0],a[1],a[2],a[3],a[4],a[5],a[6],a[7] };
    u16x8 vb = { b[0],b[1],b[2],b[3],b[4],b[5],b[6],b[7] };
    *(u16x8*)&d1[k] = va;
    *(u16x8*)&d2[k] = vb;
  }
}

// --- objB: rows 0..639 = bf16(obj), 640..1279 = bf16(|obj|), K pad 4480 -----
__global__ void k_cvt_obj(const float* __restrict__ obj, u16* __restrict__ dst)
{
  const int r = blockIdx.x;
  const int ab = (r >= 640);
  const float* src = obj + (size_t)(ab ? r-640 : r)*4424;
  for (int ch = threadIdx.x; ch < 560; ch += 256){
    const int k = ch*8;
    u16 o[8];
    #pragma unroll
    for (int i=0;i<8;i++){
      const int kk = k+i;
      float f = (kk < 4424) ? src[kk] : 0.f;
      if (ab) f = fabsf(f);
      o[i] = f2bf(f);
    }
    u16x8 vv = { o[0],o[1],o[2],o[3],o[4],o[5],o[6],o[7] };
    *(u16x8*)&dst[(size_t)r*4480 + k] = vv;
  }
}

// --- x (B,256,1024) -> xT bf16 [(b*1024+s)][c] ------------------------------
__global__ void k_xT(const float* __restrict__ x, u16* __restrict__ xT)
{
  __shared__ float t[32][33];
  const int bid = blockIdx.x;
  const int b = bid >> 8; const int cs = (bid >> 5) & 7; const int ss = bid & 31;
  const int tx = threadIdx.x & 31, ty = threadIdx.x >> 5;
  #pragma unroll
  for (int i=0;i<4;i++){
    const int r = ty + i*8;
    t[r][tx] = x[((size_t)(b*256 + cs*32 + r))*1024 + ss*32 + tx];
  }
  __syncthreads();
  #pragma unroll
  for (int i=0;i<4;i++){
    const int r = ty + i*8;
    xT[((size_t)(b*1024 + ss*32 + r))*256 + cs*32 + tx] = f2bf(t[tx][r]);
  }
}

// --- y = fc_w@xr ; mask = sigmoid(y) ----------------------------------------
__global__ void k_ymask(const float* __restrict__ x, const float* __restrict__ fcw,
                        float* __restrict__ y, float* __restrict__ mask)
{
  __shared__ float fc[1024];
  const int b = blockIdx.x >> 2, st = blockIdx.x & 3;
  for (int i=threadIdx.x; i<1024; i+=256) fc[i] = fcw[i];
  __syncthreads();
  const int s = st*256 + threadIdx.x;
  float a0=0,a1=0,a2=0,a3=0;
  for (int c=0;c<256;c++){
    const float xv = x[((size_t)(b*256+c))*1024 + s];
    a0 += fc[c]*xv; a1 += fc[256+c]*xv; a2 += fc[512+c]*xv; a3 += fc[768+c]*xv;
  }
  const size_t base = (size_t)(b*4)*1024 + s;
  y[base]        = a0; mask[base]        = 1.f/(1.f+expf(-a0));
  y[base+1024]   = a1; mask[base+1024]   = 1.f/(1.f+expf(-a1));
  y[base+2048]   = a2; mask[base+2048]   = 1.f/(1.f+expf(-a2));
  y[base+3072]   = a3; mask[base+3072]   = 1.f/(1.f+expf(-a3));
}

__global__ void k_out1(const float* __restrict__ y, float* __restrict__ out1){
  const int bn = blockIdx.x;
  float m = -3.4e38f;
  for (int s=threadIdx.x; s<1024; s+=256) m = fmaxf(m, y[(size_t)bn*1024+s]);
  for (int o=32;o;o>>=1) m = fmaxf(m, __shfl_xor(m,o));
  __shared__ float red[4];
  if ((threadIdx.x&63)==0) red[threadIdx.x>>6] = m;
  __syncthreads();
  if (threadIdx.x==0) out1[bn] = fmaxf(fmaxf(red[0],red[1]),fmaxf(red[2],red[3]));
}

// --- v[b,j,m] = sum_s vpreT[j][b*1024+s]*mask[b,m,s] ------------------------
__global__ void k_v(const float* __restrict__ vpreT, const float* __restrict__ mask,
                    float* __restrict__ v){
  const int b = blockIdx.x >> 7, j = blockIdx.x & 127;
  float a[4]={0,0,0,0};
  for (int s=threadIdx.x; s<1024; s+=256){
    const float pv = vpreT[(size_t)j*8192 + b*1024 + s];
    #pragma unroll
    for (int m=0;m<4;m++) a[m] += pv * mask[((size_t)(b*4+m))*1024 + s];
  }
  __shared__ float red[4][5];
  #pragma unroll
  for (int m=0;m<4;m++){
    float t=a[m];
    for (int o=32;o;o>>=1) t += __shfl_xor(t,o);
    if ((threadIdx.x&63)==0) red[m][threadIdx.x>>6]=t;
  }
  __syncthreads();
  if (threadIdx.x<4)
    v[(size_t)(b*128+j)*4 + threadIdx.x] =
      red[threadIdx.x][0]+red[threadIdx.x][1]+red[threadIdx.x][2]+red[threadIdx.x][3];
}

// --- lv[b,j,n] = leaky(sum_m A[n,m]*v[b,j,m]) -------------------------------
__global__ void k_lv(const float* __restrict__ Am, const float* __restrict__ v,
                     float* __restrict__ lv){
  const int idx = blockIdx.x*256 + threadIdx.x;
  if (idx < 1024){
    #pragma unroll
    for (int n=0;n<4;n++){
      float s=0;
      #pragma unroll
      for (int m=0;m<4;m++) s += Am[n*4+m]*v[idx*4+m];
      lv[idx*4+n] = lky(s);
    }
  }
}

// --- sV[b,o,n] = sum_j sw_w[o,8848+j]*lv[b,j,n] -----------------------------
__global__ void k_sV(const float* __restrict__ sw, const float* __restrict__ lv,
                     float* __restrict__ sV){
  __shared__ float l[4096];
  for (int i=threadIdx.x; i<4096; i+=256) l[i]=lv[i];
  __syncthreads();
  const int o = blockIdx.x*256 + threadIdx.x;
  if (o >= 8976) return;
  float acc[8][4] = {};
  const float* row = sw + (size_t)o*8976 + 8848;
  for (int j=0;j<128;j++){
    const float wv = row[j];
    #pragma unroll
    for (int b=0;b<8;b++){
      const float* lb = &l[(b*128+j)*4];
      #pragma unroll
      for (int n=0;n<4;n++) acc[b][n] += wv*lb[n];
    }
  }
  #pragma unroll
  for (int b=0;b<8;b++){
    f32x4 vv = {acc[b][0],acc[b][1],acc[b][2],acc[b][3]};
    *(f32x4*)&sV[((size_t)b*8976 + o)*4] = vv;
  }
}

// --- BN fold ----------------------------------------------------------------
__global__ void k_so(const float* __restrict__ cgb, const float* __restrict__ g,
                     const float* __restrict__ b2, const float* __restrict__ m,
                     const float* __restrict__ vvar, float* __restrict__ so){
  const int o = blockIdx.x*256+threadIdx.x;
  if (o<8976){
    const float sc = g[o]*rsqrtf(vvar[o]+1e-5f);
    so[o]=sc; so[8976+o] = (cgb[o]-m[o])*sc + b2[o];
  }
}

// --- glbB (bf16 mean_n hg, K pad 9088) + t2[q,o',n] = sum_c co_w2[o',c]*hg --
__global__ void k_glb_t2(const float* __restrict__ U, const float* __restrict__ obj,
                         const int* __restrict__ rel,
                         const float* __restrict__ sV, const float* __restrict__ swb,
                         const float* __restrict__ v, const float* __restrict__ Am,
                         const float* __restrict__ cow, u16* __restrict__ glbB,
                         float* __restrict__ t2)
{
  const int q = blockIdx.x; const int b = q >> 7;
  const int i1 = rel[q*2], i2 = rel[q*2+1];
  const float* u1  = U + (size_t)i1*17952;
  const float* u2  = U + (size_t)i2*17952 + 8976;
  const float* u1a = U + (size_t)(640+i1)*17952;
  const float* u2a = U + (size_t)(640+i2)*17952 + 8976;
  const float* o1 = obj + (size_t)i1*4424;
  const float* o2 = obj + (size_t)i2*4424;
  float rA[4], aA[4];
  #pragma unroll
  for (int n=0;n<4;n++){
    const float s = Am[n*4]+Am[n*4+1]+Am[n*4+2]+Am[n*4+3];
    rA[n]=0.6f*s; aA[n]=0.4f*fabsf(s);
  }
  float t2a[16] = {};
  for (int c = threadIdx.x; c < 9088; c += 256){
    if (c < 8976){
      const float p1 = u1[c] + u2[c];
      const float p2 = u1a[c] + u2a[c];
      const f32x4 sv = *(const f32x4*)&sV[((size_t)b*8976 + c)*4];
      const float sb = swb[c];
      const float gs = (c < 4424) ? o1[c] : (c < 8848) ? o2[c-4424] : 0.f;
      float hg[4]; float sum = 0.f;
      #pragma unroll
      for (int n=0;n<4;n++){
        const float xs2 = lky(rA[n]*p1 + aA[n]*p2 + sv[n] + sb);
        const float g = (c < 8848) ? gs : v[((size_t)b*128 + (c-8848))*4 + n];
        hg[n] = g + xs2; sum += hg[n];
      }
      glbB[(size_t)q*9088 + c] = f2bf(0.25f*sum);
      #pragma unroll
      for (int o4=0;o4<4;o4++){
        const float cw = cow[(size_t)o4*17952 + 8976 + c];
        #pragma unroll
        for (int n=0;n<4;n++) t2a[o4*4+n] += cw*hg[n];
      }
    } else {
      glbB[(size_t)q*9088 + c] = 0;
    }
  }
  __shared__ float red[16][5];
  #pragma unroll
  for (int i=0;i<16;i++){
    float t = t2a[i];
    for (int o=32;o;o>>=1) t += __shfl_xor(t,o);
    if ((threadIdx.x&63)==0) red[i][threadIdx.x>>6]=t;
  }
  __syncthreads();
  if (threadIdx.x < 16)
    t2[q*16+threadIdx.x] = red[threadIdx.x][0]+red[threadIdx.x][1]
                          +red[threadIdx.x][2]+red[threadIdx.x][3];
}

// --- hd with inline adj: aj = sigmoid(co1acc[q][a] + t2[q][a,m] + cob[a]) ---
__global__ void k_hd(const float* __restrict__ U, const float* __restrict__ obj,
                     const int* __restrict__ rel,
                     const float* __restrict__ sV, const float* __restrict__ swb,
                     const float* __restrict__ v, const float* __restrict__ Am,
                     const float* __restrict__ co1acc, const float* __restrict__ t2,
                     const float* __restrict__ cob, u16* __restrict__ hdb)
{
  const int q = blockIdx.x; const int b = q>>7;
  const int i1 = rel[q*2], i2 = rel[q*2+1];
  const float* u1  = U + (size_t)i1*17952;
  const float* u2  = U + (size_t)i2*17952 + 8976;
  const float* u1a = U + (size_t)(640+i1)*17952;
  const float* u2a = U + (size_t)(640+i2)*17952 + 8976;
  const float* o1 = obj + (size_t)i1*4424;
  const float* o2 = obj + (size_t)i2*4424;
  float rA[4], aA[4];
  #pragma unroll
  for (int n=0;n<4;n++){
    const float s = Am[n*4]+Am[n*4+1]+Am[n*4+2]+Am[n*4+3];
    rA[n]=0.6f*s; aA[n]=0.4f*fabsf(s);
  }
  __shared__ float aj[16];
  if (threadIdx.x<16){
    const int a_=threadIdx.x>>2, m=threadIdx.x&3;
    const float tt = co1acc[q*4+a_] + t2[q*16 + a_*4 + m] + cob[a_];
    aj[threadIdx.x] = 1.f/(1.f+expf(-tt));
  }
  __syncthreads();
  float ajr[16];
  #pragma unroll
  for (int i=0;i<16;i++) ajr[i]=aj[i];
  for (int c=threadIdx.x; c<9088; c+=256){
    if (c<8976){
      const float p1 = u1[c] + u2[c];
      const float p2 = u1a[c] + u2a[c];
      const f32x4 sv = *(const f32x4*)&sV[((size_t)b*8976 + c)*4];
      const float sb = swb[c];
      const float gs = (c < 4424) ? o1[c] : (c < 8848) ? o2[c-4424] : 0.f;
      float hg[4];
      #pragma unroll
      for (int n=0;n<4;n++){
        const float xs2 = lky(rA[n]*p1 + aA[n]*p2 + sv[n] + sb);
        const float g = (c < 8848) ? gs : v[((size_t)b*128 + (c-8848))*4 + n];
        hg[n] = g + xs2;
      }
      #pragma unroll
      for (int m=0;m<4;m++){
        const float hv = lky(hg[0]*ajr[m] + hg[1]*ajr[4+m] + hg[2]*ajr[8+m] + hg[3]*ajr[12+m]);
        hdb[((size_t)(q*4+m))*9088 + c] = f2bf(hv);
      }
    } else {
      #pragma unroll
      for (int m=0;m<4;m++) hdb[((size_t)(q*4+m))*9088 + c] = 0;
    }
  }
}

// --- final ------------------------------------------------------------------
__global__ void k_final(const float* __restrict__ o2f, const float* __restrict__ out1,
                        const float* __restrict__ llb, const float* __restrict__ mm,
                        float* __restrict__ out)
{
  const int idx = blockIdx.x*256+threadIdx.x;
  if (idx < 4096){
    const int q = idx>>2, o = idx&3, b = q>>7;
    float s=0.f;
    #pragma unroll
    for (int m=0;m<4;m++) s += lky(o2f[(q*4+o)*4+m] + llb[o]) * mm[o*4+m];
    out[idx] = 0.5f*(out1[b*4+o] + s);
  }
}

extern "C" void kernel_launch(void* const* d_in, const int* in_sizes, int n_in,
                              void* d_out, int out_size, void* d_ws, size_t ws_size,
                              hipStream_t stream)
{
  const float* x    = (const float*)d_in[0];
  const int*   rel  = (const int*)d_in[1];
  const float* obj  = (const float*)d_in[2];
  const float* fcw  = (const float*)d_in[3];
  const float* ctw  = (const float*)d_in[4];
  const float* ctb  = (const float*)d_in[5];
  const float* Am   = (const float*)d_in[6];
  const float* sww  = (const float*)d_in[7];
  const float* swb  = (const float*)d_in[8];
  const float* cgw  = (const float*)d_in[9];
  const float* cgb  = (const float*)d_in[10];
  const float* bng  = (const float*)d_in[11];
  const float* bnb  = (const float*)d_in[12];
  const float* bnm  = (const float*)d_in[13];
  const float* bnv  = (const float*)d_in[14];
  const float* cow  = (const float*)d_in[15];
  const float* cob  = (const float*)d_in[16];
  const float* dww  = (const float*)d_in[17];
  const float* dwb  = (const float*)d_in[18];
  const float* llw  = (const float*)d_in[19];
  const float* llb  = (const float*)d_in[20];
  const float* mm   = (const float*)d_in[21];
  float* out = (float*)d_out;
  (void)in_sizes; (void)n_in; (void)out_size; (void)ws_size;

  char* ws = (char*)d_ws;
  size_t off = 0;
  auto alloc = [&](size_t bytes)->char*{
    char* p = ws + off; off = (off + bytes + 255) & ~(size_t)255; return p;
  };
  u16*   Wb    = (u16*)  alloc((size_t)9216*9088*2);   // serial reuse; fits 18176x4480
  float* U     = (float*)alloc((size_t)1280*17952*4);
  u16*   glbB  = (u16*)  alloc((size_t)1024*9088*2);
  u16*   hdb   = (u16*)  alloc((size_t)4096*9088*2);
  u16*   objB  = (u16*)  alloc((size_t)1280*4480*2);
  float* glb2  = (float*)alloc((size_t)1024*8976*4);
  u16*   xT    = (u16*)  alloc((size_t)8192*256*2);
  u16*   ctwb  = (u16*)  alloc((size_t)128*256*2);
  float* y     = (float*)alloc((size_t)32768*4);
  float* mask  = (float*)alloc((size_t)32768*4);
  float* out1  = (float*)alloc((size_t)32*4);
  float* vpreT = (float*)alloc((size_t)128*8192*4);
  float* v     = (float*)alloc((size_t)4096*4);
  float* lv    = (float*)alloc((size_t)4096*4);
  float* sV    = (float*)alloc((size_t)287232*4);
  float* so    = (float*)alloc((size_t)2*8976*4);
  float* t2    = (float*)alloc((size_t)16384*4);
  float* co1a  = (float*)alloc((size_t)4096*4);
  float* o2f   = (float*)alloc((size_t)16384*4);

  // stage 1: small precomputes
  k_xT<<<dim3(2048), dim3(256), 0, stream>>>(x, xT);
  k_cvt_pad<<<dim3(128), dim3(256), 0, stream>>>(ctw, 128, 256, 256, 0, ctwb, 256);
  k_ymask<<<dim3(32), dim3(256), 0, stream>>>(x, fcw, y, mask);
  k_out1<<<dim3(32), dim3(256), 0, stream>>>(y, out1);
  gemm_vpre<<<dim3(64), dim3(256), 0, stream>>>(
      ctwb, xT, 256, 64, 128, vpreT, (long long)8192, ctb);
  k_v<<<dim3(1024), dim3(256), 0, stream>>>(vpreT, mask, v);

  // stage 2: U = [W_F_left; W_F_right] @ [obj; |obj|]^T (Kp 4480, NT=70)
  k_cvt_obj<<<dim3(1280), dim3(256), 0, stream>>>(obj, objB);
  k_cvt_sww<<<dim3(8976), dim3(256), 0, stream>>>(sww, Wb);
  gemmU<0><<<dim3(71*5), dim3(1024), 0, stream>>>(
      Wb, objB, 4480, 5, 5, 17952, U, (long long)17952,
      nullptr, nullptr, nullptr, nullptr, nullptr);

  // stage 3: sV, glb, t2
  k_lv<<<dim3(4), dim3(256), 0, stream>>>(Am, v, lv);
  k_sV<<<dim3(36), dim3(256), 0, stream>>>(sww, lv, sV);
  k_glb_t2<<<dim3(1024), dim3(256), 0, stream>>>(U, obj, rel, sV, swb, v, Am,
                                                 cow, glbB, t2);

  // stage 4: GEMM2 (Kp 9088, NT=142) + fused co1 reduction (cow passed as llw,
  // co1acc as oacc)
  k_cvt_pad<<<dim3(9216), dim3(256), 0, stream>>>(cgw, 8976, 8976, 8976, 0, Wb, 9088);
  k_so<<<dim3(36), dim3(256), 0, stream>>>(cgb, bng, bnb, bnm, bnv, so);
  hipMemsetAsync(co1a, 0, (size_t)4096*4, stream);
  gemmU<2><<<dim3(36*4), dim3(1024), 0, stream>>>(
      Wb, glbB, 9088, 4, 4, 8976, glb2, (long long)8976,
      nullptr, so, so + 8976, cow, co1a);

  // stage 5: hd (adj computed inline from co1a + t2 + cob)
  k_cvt_pad<<<dim3(9216), dim3(256), 0, stream>>>(dww, 8976, 8976, 8976, 0, Wb, 9088);
  k_hd<<<dim3(1024), dim3(256), 0, stream>>>(U, obj, rel, sV, swb, v, Am,
                                             co1a, t2, cob, hdb);

  // stage 6: GEMM3 (Kp 9088, SN=8 supertile) fused diagonal ll_w reduction
  hipMemsetAsync(o2f, 0, (size_t)16384*4, stream);
  gemmU<3><<<dim3(36*16), dim3(1024), 0, stream>>>(
      Wb, hdb, 9088, 16, 8, 8976, nullptr, 0, dwb,
      nullptr, nullptr, llw, o2f);

  // stage 7: final combine
  k_final<<<dim3(16), dim3(256), 0, stream>>>(o2f, out1, llb, mm, out);
}